// Round 15
// baseline (19.656 us; speedup 1.0000x reference)
//
#include <hip/hip_runtime.h>
#include <math.h>

#define RPOOL 5

// 4-byte-aligned float4: gfx950 global loads support dword-aligned dwordx4.
typedef float float4u __attribute__((ext_vector_type(4), aligned(4)));

template <int CTRL>
__device__ __forceinline__ float dpp_mov(float v) {
    const int iv = __float_as_int(v);
    const int o  = __builtin_amdgcn_update_dpp(iv, iv, CTRL, 0xf, 0xf, false);
    return __int_as_float(o);
}

// 16-lane-group butterfly (masks {1,2,7,15} span GF(2)^4; max/min idempotent
// so every lane of the group ends with the group reduce). All intra-row DPP.
__device__ __forceinline__ float grp_fmax(float v) {
    v = fmaxf(v, dpp_mov<0xB1>(v));    // quad_perm [1,0,3,2] : xor 1
    v = fmaxf(v, dpp_mov<0x4E>(v));    // quad_perm [2,3,0,1] : xor 2
    v = fmaxf(v, dpp_mov<0x141>(v));   // row_half_mirror     : xor 7
    v = fmaxf(v, dpp_mov<0x140>(v));   // row_mirror          : xor 15
    return v;
}
__device__ __forceinline__ float grp_fmin(float v) {
    v = fminf(v, dpp_mov<0xB1>(v));
    v = fminf(v, dpp_mov<0x4E>(v));
    v = fminf(v, dpp_mov<0x141>(v));
    v = fminf(v, dpp_mov<0x140>(v));
    return v;
}

__global__ __launch_bounds__(256, 8)
void minmax_pool_sort_kernel(const float* __restrict__ x,
                             const int* __restrict__ lengths,
                             float* __restrict__ out,
                             int n, int L) {
    // 16 lanes per row: block of 256 handles 16 rows (4 rows per wave).
    const int sub = threadIdx.x & 15;
    const int row = blockIdx.x * 16 + (threadIdx.x >> 4);
    if (row >= n) return;

    const int lv = lengths[row];                  // group-uniform length
    const float* xr = x + (long long)row * L;
    const int sub4 = sub * 4;

    float mx[RPOOL], mn[RPOOL];

    if (!__any(lv < 4 * RPOOL)) {
        // ---------- FAST PATH (all 4 rows have l >= 20): mask-free clamp-loads ----
        // Window size = ceil((j+1)l/5)-floor(jl/5) <= (l+8)/5 = floor(l/5)+2
        // (NOT +1: both fractional corrections can hit, e.g. l%5==2, j=2).
        // Subload k needed iff size > 64k <= (l+8)/5 > 64k <=> l > 320k-8.
        // Conservative wave-uniform flags (thresholds 313/633/953).
        const bool need1 = __any(lv >= 320 - 7);
        const bool need2 = __any(lv >= 640 - 7);
        const bool need3 = __any(lv >= 960 - 7);
#pragma unroll
        for (int j = 0; j < RPOOL; ++j) {
            const int s   = (j * lv) / RPOOL;                    // floor(j*l/R)
            const int e   = ((j + 1) * lv + RPOOL - 1) / RPOOL;  // ceil((j+1)*l/R)
            const int cap = e - 4;
            float mxw, mnw;
            {   // subload 0 (always)
                int idx = s + sub4;
                idx = (idx < cap) ? idx : cap;
                const float4u v = *reinterpret_cast<const float4u*>(xr + idx);
                mxw = fmaxf(fmaxf(v.x, v.y), fmaxf(v.z, v.w));
                mnw = fminf(fminf(v.x, v.y), fminf(v.z, v.w));
            }
            if (need1) {
                int idx = s + sub4 + 64;
                idx = (idx < cap) ? idx : cap;
                const float4u v = *reinterpret_cast<const float4u*>(xr + idx);
                mxw = fmaxf(mxw, fmaxf(fmaxf(v.x, v.y), fmaxf(v.z, v.w)));
                mnw = fminf(mnw, fminf(fminf(v.x, v.y), fminf(v.z, v.w)));
            }
            if (need2) {
                int idx = s + sub4 + 128;
                idx = (idx < cap) ? idx : cap;
                const float4u v = *reinterpret_cast<const float4u*>(xr + idx);
                mxw = fmaxf(mxw, fmaxf(fmaxf(v.x, v.y), fmaxf(v.z, v.w)));
                mnw = fminf(mnw, fminf(fminf(v.x, v.y), fminf(v.z, v.w)));
            }
            if (need3) {
                int idx = s + sub4 + 192;
                idx = (idx < cap) ? idx : cap;
                const float4u v = *reinterpret_cast<const float4u*>(xr + idx);
                mxw = fmaxf(mxw, fmaxf(fmaxf(v.x, v.y), fmaxf(v.z, v.w)));
                mnw = fminf(mnw, fminf(fminf(v.x, v.y), fminf(v.z, v.w)));
            }
            mx[j] = grp_fmax(mxw);
            mn[j] = grp_fmin(mnw);
        }
    } else {
        // ---------- SLOW PATH (~6% of waves): exact masked loads, any l >= 1 ----
#pragma unroll
        for (int j = 0; j < RPOOL; ++j) {
            const int s  = (j * lv) / RPOOL;
            const int e  = ((j + 1) * lv + RPOOL - 1) / RPOOL;
            const int sa = s & ~3;                 // aligned head
            float mxw = -INFINITY, mnw = INFINITY;
#pragma unroll
            for (int k = 0; k < 4; ++k) {
                const int t = sa + sub4 + k * 64;
                const int idx = (t < e) ? t : 0;   // clamp into row; masked below
                const float4u v = *reinterpret_cast<const float4u*>(xr + idx);
                const bool ok0 = (t     >= s) & (t     < e);
                const bool ok1 = (t + 1 >= s) & (t + 1 < e);
                const bool ok2 = (t + 2 >= s) & (t + 2 < e);
                const bool ok3 = (t + 3 >= s) & (t + 3 < e);
                mxw = fmaxf(mxw, ok0 ? v.x : -INFINITY);
                mxw = fmaxf(mxw, ok1 ? v.y : -INFINITY);
                mxw = fmaxf(mxw, ok2 ? v.z : -INFINITY);
                mxw = fmaxf(mxw, ok3 ? v.w : -INFINITY);
                mnw = fminf(mnw, ok0 ? v.x :  INFINITY);
                mnw = fminf(mnw, ok1 ? v.y :  INFINITY);
                mnw = fminf(mnw, ok2 ? v.z :  INFINITY);
                mnw = fminf(mnw, ok3 ? v.w :  INFINITY);
            }
            mx[j] = grp_fmax(mxw);
            mn[j] = grp_fmin(mnw);
        }
    }

    float vals[2 * RPOOL];
#pragma unroll
    for (int j = 0; j < RPOOL; ++j) { vals[j] = mx[j]; vals[RPOOL + j] = mn[j]; }

    // Sort 10 ascending — fully-unrolled bubble network (known correct).
#pragma unroll
    for (int i = 0; i < 2 * RPOOL - 1; ++i) {
#pragma unroll
        for (int k = 0; k < 2 * RPOOL - 1 - i; ++k) {
            const float a = vals[k];
            const float b = vals[k + 1];
            vals[k]     = fminf(a, b);
            vals[k + 1] = fmaxf(a, b);
        }
    }

    // Store: lanes 0..9 of each 16-lane group store their row's 10 values.
    float ov = vals[0];
#pragma unroll
    for (int k = 1; k < 2 * RPOOL; ++k) ov = (sub == k) ? vals[k] : ov;
    if (sub < 2 * RPOOL) out[(long long)row * (2 * RPOOL) + sub] = ov;
}

extern "C" void kernel_launch(void* const* d_in, const int* in_sizes, int n_in,
                              void* d_out, int out_size, void* d_ws, size_t ws_size,
                              hipStream_t stream) {
    const float* x       = (const float*)d_in[0];
    const int*   lengths = (const int*)d_in[1];
    float*       out     = (float*)d_out;

    const int n = in_sizes[1];            // N rows
    const int L = in_sizes[0] / n;        // row stride (1000)

    const int blocks = (n + 15) / 16;     // 16 rows per 256-thread block
    hipLaunchKernelGGL(minmax_pool_sort_kernel, dim3(blocks), dim3(256), 0, stream,
                       x, lengths, out, n, L);
}

// Round 16
// 18.862 us; speedup vs baseline: 1.0421x; 1.0421x over previous
//
#include <hip/hip_runtime.h>
#include <math.h>

#define RPOOL 5

// 4-byte-aligned float4: gfx950 global loads support dword-aligned dwordx4.
typedef float float4u __attribute__((ext_vector_type(4), aligned(4)));

template <int CTRL>
__device__ __forceinline__ float dpp_mov(float v) {
    const int iv = __float_as_int(v);
    const int o  = __builtin_amdgcn_update_dpp(iv, iv, CTRL, 0xf, 0xf, false);
    return __int_as_float(o);
}

// 16-lane-group butterfly (masks {1,2,7,15} span GF(2)^4; max/min idempotent
// so every lane of the group ends with the group reduce). All intra-row DPP:
// v_max_f32 is VOP2 -> backend fuses the dpp mov into the max operand.
__device__ __forceinline__ float grp_fmax(float v) {
    v = fmaxf(v, dpp_mov<0xB1>(v));    // quad_perm [1,0,3,2] : xor 1
    v = fmaxf(v, dpp_mov<0x4E>(v));    // quad_perm [2,3,0,1] : xor 2
    v = fmaxf(v, dpp_mov<0x141>(v));   // row_half_mirror     : xor 7
    v = fmaxf(v, dpp_mov<0x140>(v));   // row_mirror          : xor 15
    return v;
}
__device__ __forceinline__ float grp_fmin(float v) {
    v = fminf(v, dpp_mov<0xB1>(v));
    v = fminf(v, dpp_mov<0x4E>(v));
    v = fminf(v, dpp_mov<0x141>(v));
    v = fminf(v, dpp_mov<0x140>(v));
    return v;
}

__global__ __launch_bounds__(256, 8)
void minmax_pool_sort_kernel(const float* __restrict__ x,
                             const int* __restrict__ lengths,
                             float* __restrict__ out,
                             int n, int L) {
    // 16 lanes per row: block of 256 handles 16 rows (4 rows per wave).
    const int sub = threadIdx.x & 15;
    const int row = blockIdx.x * 16 + (threadIdx.x >> 4);
    if (row >= n) return;

    const int lv = lengths[row];                  // group-uniform length
    const float* xr = x + (long long)row * L;
    const int sub4 = sub * 4;

    float mx[RPOOL], mn[RPOOL];

    if (!__any(lv < 4 * RPOOL)) {
        // ---------- FAST PATH (all 4 rows have l >= 20): mask-free clamp-loads ----
        // Window j = [s,e), size >= 4. Sub-load k covers raw [s+64k+4*sub, +4);
        // clamp idx to e-4 keeps every element in [s,e) (dups harmless) and the
        // clamped loads cover the tail. 4 sub-loads cover size <= 256 >= 202 max.
        // NOTE (R15 lesson): always-4 unconditional subloads beat wave-uniform
        // skip-branches — branches fence the VMEM clause and cost more MLP
        // than the skipped work saves (18.47 vs 19.66 us measured).
#pragma unroll
        for (int j = 0; j < RPOOL; ++j) {
            const int s   = (j * lv) / RPOOL;                    // floor(j*l/R)
            const int e   = ((j + 1) * lv + RPOOL - 1) / RPOOL;  // ceil((j+1)*l/R)
            const int cap = e - 4;
            float mxw = -INFINITY, mnw = INFINITY;
#pragma unroll
            for (int k = 0; k < 4; ++k) {
                int idx = s + sub4 + k * 64;
                idx = (idx < cap) ? idx : cap;
                const float4u v = *reinterpret_cast<const float4u*>(xr + idx);
                mxw = fmaxf(mxw, fmaxf(fmaxf(v.x, v.y), fmaxf(v.z, v.w)));
                mnw = fminf(mnw, fminf(fminf(v.x, v.y), fminf(v.z, v.w)));
            }
            mx[j] = grp_fmax(mxw);
            mn[j] = grp_fmin(mnw);
        }
    } else {
        // ---------- SLOW PATH (~6% of waves): exact masked loads, any l >= 1 ----
#pragma unroll
        for (int j = 0; j < RPOOL; ++j) {
            const int s  = (j * lv) / RPOOL;
            const int e  = ((j + 1) * lv + RPOOL - 1) / RPOOL;
            const int sa = s & ~3;                 // aligned head
            float mxw = -INFINITY, mnw = INFINITY;
#pragma unroll
            for (int k = 0; k < 4; ++k) {
                const int t = sa + sub4 + k * 64;
                const int idx = (t < e) ? t : 0;   // clamp into row; masked below
                const float4u v = *reinterpret_cast<const float4u*>(xr + idx);
                const bool ok0 = (t     >= s) & (t     < e);
                const bool ok1 = (t + 1 >= s) & (t + 1 < e);
                const bool ok2 = (t + 2 >= s) & (t + 2 < e);
                const bool ok3 = (t + 3 >= s) & (t + 3 < e);
                mxw = fmaxf(mxw, ok0 ? v.x : -INFINITY);
                mxw = fmaxf(mxw, ok1 ? v.y : -INFINITY);
                mxw = fmaxf(mxw, ok2 ? v.z : -INFINITY);
                mxw = fmaxf(mxw, ok3 ? v.w : -INFINITY);
                mnw = fminf(mnw, ok0 ? v.x :  INFINITY);
                mnw = fminf(mnw, ok1 ? v.y :  INFINITY);
                mnw = fminf(mnw, ok2 ? v.z :  INFINITY);
                mnw = fminf(mnw, ok3 ? v.w :  INFINITY);
            }
            mx[j] = grp_fmax(mxw);
            mn[j] = grp_fmin(mnw);
        }
    }

    float vals[2 * RPOOL];
#pragma unroll
    for (int j = 0; j < RPOOL; ++j) { vals[j] = mx[j]; vals[RPOOL + j] = mn[j]; }

    // Sort 10 ascending — fully-unrolled bubble network (known correct).
    // Shared by all 4 rows of the wave (amortized 4x).
#pragma unroll
    for (int i = 0; i < 2 * RPOOL - 1; ++i) {
#pragma unroll
        for (int k = 0; k < 2 * RPOOL - 1 - i; ++k) {
            const float a = vals[k];
            const float b = vals[k + 1];
            vals[k]     = fminf(a, b);
            vals[k + 1] = fmaxf(a, b);
        }
    }

    // Store: lanes 0..9 of each 16-lane group store their row's 10 values.
    float ov = vals[0];
#pragma unroll
    for (int k = 1; k < 2 * RPOOL; ++k) ov = (sub == k) ? vals[k] : ov;
    if (sub < 2 * RPOOL) out[(long long)row * (2 * RPOOL) + sub] = ov;
}

extern "C" void kernel_launch(void* const* d_in, const int* in_sizes, int n_in,
                              void* d_out, int out_size, void* d_ws, size_t ws_size,
                              hipStream_t stream) {
    const float* x       = (const float*)d_in[0];
    const int*   lengths = (const int*)d_in[1];
    float*       out     = (float*)d_out;

    const int n = in_sizes[1];            // N rows
    const int L = in_sizes[0] / n;        // row stride (1000)

    const int blocks = (n + 15) / 16;     // 16 rows per 256-thread block
    hipLaunchKernelGGL(minmax_pool_sort_kernel, dim3(blocks), dim3(256), 0, stream,
                       x, lengths, out, n, L);
}